// Round 2
// baseline (123.686 us; speedup 1.0000x reference)
//
#include <hip/hip_runtime.h>

#define TT 14
#define LL 26
#define EE 128
#define NB 16384
#define BPB 8              // batches per block
#define ROWS (BPB * TT)    // 112 (b,t) rows per block
#define CH 16              // e-elements staged per chunk
#define XPAD 17            // odd pad -> bank bijection for per-row reads
#define EPAD 27            // odd pad -> conflict-free emis writes/reads

// ---------------------------------------------------------------------------
// Setup: fold conv into an effective emission matrix.
//   Weff[e][l] = sum_{ky,kx} conv_w[ky][kx] * Wmat[l][oy*8+ox]
//   be[l]      = conv_b * sum_e Wmat[l][e]
// ---------------------------------------------------------------------------
__global__ __launch_bounds__(256) void crf_setup(
    const float* __restrict__ conv_w, const float* __restrict__ conv_b,
    const float* __restrict__ params, float* __restrict__ weff,
    float* __restrict__ be) {
  int idx = blockIdx.x * 256 + threadIdx.x;
  if (idx < EE * LL) {
    int e = idx / LL, l = idx - e * LL;
    int iy = e >> 3, ix = e & 7;
    float s = 0.f;
    for (int ky = 0; ky < 5; ++ky) {
      int oy = iy - ky + 2;
      if (oy < 0 || oy >= 16) continue;
      for (int kx = 0; kx < 5; ++kx) {
        int ox = ix - kx + 2;
        if (ox < 0 || ox >= 8) continue;
        s += conv_w[ky * 5 + kx] * params[l * EE + oy * 8 + ox];
      }
    }
    weff[e * LL + l] = s;  // [e][l]: main-kernel reads are wave-uniform
  }
  if (idx < LL) {
    float s = 0.f;
    for (int e = 0; e < EE; ++e) s += params[idx * EE + e];
    be[idx] = conv_b[0] * s;
  }
}

// ---------------------------------------------------------------------------
// Fused emission GEMM + Viterbi + backtrack. One block = 8 batches.
// ---------------------------------------------------------------------------
__global__ __launch_bounds__(128, 4) void crf_main(
    const float* __restrict__ X, const float* __restrict__ params,
    const float* __restrict__ weff, const float* __restrict__ be,
    float* __restrict__ out) {
  __shared__ float emis_s[ROWS * EPAD];   // 12.1 KB
  __shared__ float Ts[LL * LL];           // 2.7 KB
  __shared__ float uni[ROWS * XPAD];      // 7.6 KB: xs | (bp + preds + score)
  unsigned char* bp_s = (unsigned char*)uni;     // [BPB][13][28] = 2912 B
  float* preds_s = uni + (BPB * 13 * 28) / 4;    // 112 floats
  float* score_s = preds_s + ROWS;               // 8 floats

  const int tid = threadIdx.x;
  const int b0 = blockIdx.x * BPB;

  for (int i = tid; i < LL * LL; i += 128) Ts[i] = params[LL * EE + i];

  // ---- Phase 1: emissions, LDS-staged coalesced X loads.
  float acc[LL];
#pragma unroll
  for (int l = 0; l < LL; ++l) acc[l] = 0.f;
  const float4* Xv = reinterpret_cast<const float4*>(X) + (size_t)b0 * TT * 32;

  for (int c = 0; c < EE / CH; ++c) {
    __syncthreads();  // previous chunk's consumers done before overwrite
#pragma unroll
    for (int k = 0; k < 4; ++k) {
      int fid = k * 128 + tid;
      if (fid < ROWS * 4) {            // 448 float4s per chunk
        int row = fid >> 2, q = fid & 3;
        float4 v = Xv[row * 32 + c * 4 + q];
        float* xp = &uni[row * XPAD + q * 4];
        xp[0] = v.x; xp[1] = v.y; xp[2] = v.z; xp[3] = v.w;
      }
    }
    __syncthreads();
    if (tid < ROWS) {
      const float* w = weff + c * CH * LL;  // wave-uniform -> s_load
#pragma unroll
      for (int e = 0; e < CH; ++e) {
        float xv = uni[tid * XPAD + e];
#pragma unroll
        for (int l = 0; l < LL; ++l) acc[l] += xv * w[e * LL + l];
      }
    }
  }
  if (tid < ROWS) {
#pragma unroll
    for (int l = 0; l < LL; ++l) emis_s[tid * EPAD + l] = acc[l] + be[l];
  }
  __syncthreads();  // emis ready; uni free for bp/preds

  // ---- Phase 2: Viterbi. 32-lane group per batch, lane j = label.
  const int lane = tid & 63;
  const int wv = tid >> 6;                 // wave 0..1
  const int j = lane & 31;
  const int hb = lane >> 5;
  const int jj = (j < LL) ? j : (LL - 1);

  for (int p = 0; p < 2; ++p) {
    const int bl = p * 4 + wv * 2 + hb;    // 0..7
    float Tcol[LL];
#pragma unroll
    for (int i = 0; i < LL; ++i) Tcol[i] = Ts[i * LL + jj];  // Trans[i][j]

    float alpha = emis_s[(bl * TT + 0) * EPAD + jj];
    for (int t = 1; t < TT; ++t) {
      float m = -__builtin_inff();
      int bp = 0;
#pragma unroll
      for (int i = 0; i < LL; ++i) {
        float a_i = __shfl(alpha, i, 32);
        float s = a_i + Tcol[i];
        if (s > m) { m = s; bp = i; }      // strict > : first-index tie-break
      }
      alpha = m + emis_s[(bl * TT + t) * EPAD + jj];
      if (j < LL) bp_s[(bl * 13 + (t - 1)) * 28 + j] = (unsigned char)bp;
    }

    float val = (j < LL) ? alpha : -__builtin_inff();
    int idx = j;
#pragma unroll
    for (int off = 16; off >= 1; off >>= 1) {
      float v2 = __shfl_xor(val, off, 32);
      int i2 = __shfl_xor(idx, off, 32);
      if (v2 > val || (v2 == val && i2 < idx)) { val = v2; idx = i2; }
    }

    __syncthreads();  // bp_s visible (and uni reads done before p=0 writes)

    if (j == 0) {
      score_s[bl] = val;
      int lbl = idx;
      for (int t = TT - 1; t >= 1; --t) {
        preds_s[bl * TT + t] = (float)lbl;
        lbl = bp_s[(bl * 13 + (t - 1)) * 28 + lbl];
      }
      preds_s[bl * TT + 0] = (float)lbl;
    }
    __syncthreads();
  }

  // ---- Coalesced output write.
  if (tid < ROWS) {
    out[(size_t)b0 * TT + tid] = preds_s[tid];
  } else if (tid < ROWS + BPB) {
    out[(size_t)NB * TT + b0 + (tid - ROWS)] = score_s[tid - ROWS];
  }
}

extern "C" void kernel_launch(void* const* d_in, const int* in_sizes, int n_in,
                              void* d_out, int out_size, void* d_ws,
                              size_t ws_size, hipStream_t stream) {
  const float* X = (const float*)d_in[0];
  const float* conv_w = (const float*)d_in[1];
  const float* conv_b = (const float*)d_in[2];
  const float* params = (const float*)d_in[3];
  float* out = (float*)d_out;
  float* weff = (float*)d_ws;  // 3328 floats
  float* be = weff + EE * LL;  // 26 floats

  hipLaunchKernelGGL(crf_setup, dim3(13), dim3(256), 0, stream, conv_w, conv_b,
                     params, weff, be);
  hipLaunchKernelGGL(crf_main, dim3(NB / BPB), dim3(128), 0, stream, X, params,
                     weff, be, out);
}